// Round 7
// baseline (424.633 us; speedup 1.0000x reference)
//
#include <hip/hip_runtime.h>
#include <stdint.h>

// MPNN layer, dst-sorted edge processing (R7): barrier-free per-wave msg kernel.
//  - counting-sort edges by dst
//  - msg kernel: each WAVE owns 16 sorted edges, fully independent:
//    A-fragments loaded directly from global (no LDS A-tile, no gather
//    barrier), per-wave Hs strip for the GEMM1->GEMM2 transpose only,
//    in-register f32 segmented reduction via ballot/shfl -> 2 atomics/lane/run.
//    LDS 18.4KB -> cap 8 blocks/CU; occupancy limited by VGPR only.
//    NO min-waves launch bound (R3: forced spill of the accumulators).
//  - upd kernel: node MLP + residual (R6 version, passed post-timing).

#define N_NODES 100000
#define N_EDGES 800000
#define NODE_DIM 64
#define EDGE_DIM 32
#define HIDDEN 128
#define LN_EPS 1e-5f

#define PH 136   // Hs pitch (bf16 elems), 128 data cols
#define PU 200   // upd A-tile pitch (bf16 elems), 192 data cols

#define NB_SCAN ((N_NODES + 1023) / 1024)   // 98
#define MSG_NWG (N_EDGES / 64)              // 12500 = 8*1562 + 4

typedef __attribute__((ext_vector_type(8))) short short8;
typedef __attribute__((ext_vector_type(4))) float f32x4;
typedef __attribute__((ext_vector_type(4))) uint32_t u32x4;

static __device__ __forceinline__ uint16_t f2bf(float f) {
  uint32_t u = __float_as_uint(f);
  return (uint16_t)((u + 0x7FFFu + ((u >> 16) & 1u)) >> 16);
}
static __device__ __forceinline__ float bf2f(uint16_t u) {
  return __uint_as_float(((uint32_t)u) << 16);
}

// ---------------- fused prepass: cvt_x + hist + pack all weights ----------------

#define PREP_CVT_BLKS 6250
#define PREP_HIST_BLKS 3125

__global__ void prep_kernel(const float* __restrict__ x, uint16_t* __restrict__ xb,
                            const int* __restrict__ ei, int* __restrict__ cnt,
                            const float* __restrict__ W1, uint16_t* __restrict__ W1p,
                            const float* __restrict__ W2, uint16_t* __restrict__ W2p,
                            const float* __restrict__ Wu1, uint16_t* __restrict__ Wu1p,
                            const float* __restrict__ Wu2, uint16_t* __restrict__ Wu2p) {
  int b = blockIdx.x;
  if (b < PREP_CVT_BLKS) {
    int i = b * 256 + threadIdx.x;           // quad index
    if (i * 4 < N_NODES * NODE_DIM) {
      float4 f = *(const float4*)(x + (size_t)i * 4);
      ushort4 o;
      o.x = f2bf(f.x); o.y = f2bf(f.y); o.z = f2bf(f.z); o.w = f2bf(f.w);
      *(ushort4*)(xb + (size_t)i * 4) = o;
    }
    return;
  }
  if (b < PREP_CVT_BLKS + PREP_HIST_BLKS) {
    int e = (b - PREP_CVT_BLKS) * 256 + threadIdx.x;
    if (e < N_EDGES) atomicAdd(&cnt[ei[N_EDGES + e]], 1);
    return;
  }
  int i = (b - PREP_CVT_BLKS - PREP_HIST_BLKS) * 256 + threadIdx.x;
  const float* W; uint16_t* dst; int K, C;
  if (i < 20480)      { W = W1;  dst = W1p;  K = 160; C = 128; }
  else if (i < 36864) { W = W2;  dst = W2p;  K = 128; C = 128; i -= 20480; }
  else if (i < 61440) { W = Wu1; dst = Wu1p; K = 192; C = 128; i -= 36864; }
  else if (i < 69632) { W = Wu2; dst = Wu2p; K = 128; C = 64;  i -= 61440; }
  else return;
  int k = i / C, c = i % C;
  dst[(((k >> 5) * C + c) * 4 + ((k >> 3) & 3)) * 8 + (k & 7)] = f2bf(W[i]);
}

// ---------------- counting sort by dst ----------------

__global__ __launch_bounds__(256) void scan_blk(const int* __restrict__ cnt,
                                                int* __restrict__ offs,
                                                int* __restrict__ bsum) {
  __shared__ int wsum[4];
  int tid = threadIdx.x;
  int base = blockIdx.x * 1024 + tid * 4;
  int v0 = 0, v1 = 0, v2 = 0, v3 = 0;
  if (base < N_NODES) v0 = cnt[base];
  if (base + 1 < N_NODES) v1 = cnt[base + 1];
  if (base + 2 < N_NODES) v2 = cnt[base + 2];
  if (base + 3 < N_NODES) v3 = cnt[base + 3];
  int tsum = v0 + v1 + v2 + v3;
  int lane = tid & 63, wid = tid >> 6;
  int s = tsum;
  #pragma unroll
  for (int d = 1; d < 64; d <<= 1) {
    int t = __shfl_up(s, d);
    if (lane >= d) s += t;
  }
  if (lane == 63) wsum[wid] = s;
  __syncthreads();
  int woff = 0;
  for (int w = 0; w < wid; ++w) woff += wsum[w];
  int excl = woff + s - tsum;
  if (base < N_NODES) {
    int run = excl;
    offs[base] = run; run += v0;
    if (base + 1 < N_NODES) { offs[base + 1] = run; run += v1; }
    if (base + 2 < N_NODES) { offs[base + 2] = run; run += v2; }
    if (base + 3 < N_NODES) { offs[base + 3] = run; run += v3; }
  }
  if (tid == 255) bsum[blockIdx.x] = woff + s;
}

__global__ void scan_top(int* __restrict__ bsum) {
  __shared__ int sh[128];
  int tid = threadIdx.x;
  int v = (tid < NB_SCAN) ? bsum[tid] : 0;
  int orig = v;
  sh[tid] = v;
  __syncthreads();
  for (int d = 1; d < 128; d <<= 1) {
    int t = (tid >= d) ? sh[tid - d] : 0;
    __syncthreads();
    v += t;
    sh[tid] = v;
    __syncthreads();
  }
  if (tid < NB_SCAN) bsum[tid] = v - orig;
}

__global__ void scan_add(const int* __restrict__ offs, const int* __restrict__ bsum,
                         int* __restrict__ cursor) {
  int i = blockIdx.x * 256 + threadIdx.x;
  if (i < N_NODES) cursor[i] = offs[i] + bsum[i >> 10];
}

__global__ void scatter_edges(const int* __restrict__ ei, int* __restrict__ cursor,
                              int* __restrict__ src_s, int* __restrict__ dst_s,
                              int* __restrict__ eid_s) {
  int e = blockIdx.x * 256 + threadIdx.x;
  if (e < N_EDGES) {
    int s = ei[e], d = ei[N_EDGES + e];
    int p = atomicAdd(&cursor[d], 1);
    src_s[p] = s; dst_s[p] = d; eid_s[p] = e;
  }
}

// ---------------- message kernel: barrier-free, per-wave ----------------

__global__ __launch_bounds__(256) void msg_kernel(
    const int* __restrict__ src_s, const int* __restrict__ dst_s,
    const int* __restrict__ eid_s,
    const float* __restrict__ ea, const uint16_t* __restrict__ xb,
    const uint16_t* __restrict__ W1p, const float* __restrict__ b1,
    const float* __restrict__ g1, const float* __restrict__ be1,
    const uint16_t* __restrict__ W2p, const float* __restrict__ b2,
    float* __restrict__ agg) {
  // LDS: per-wave Hs strip (GEMM1->GEMM2 transpose only) + bf16 params.
  // 4*16*136*2 + 4*128*2 = 18432 B -> 8 blocks/CU by LDS.
  __shared__ __align__(16) uint16_t Hs[4 * 16 * PH];
  __shared__ uint16_t sb1h[128], sgh[128], sbeh[128], sb2h[128];

  const int tid = threadIdx.x;
  if (tid < 128) { sb1h[tid] = f2bf(b1[tid]); sgh[tid] = f2bf(g1[tid]); }
  else { sbeh[tid - 128] = f2bf(be1[tid - 128]); sb2h[tid - 128] = f2bf(b2[tid - 128]); }
  __syncthreads();   // the only block-wide barrier

  // bijective XCD-chunk swizzle (nwg = 12500 = 8*1562 + 4): dst-adjacent
  // blocks land on the same XCD -> agg atomic-line locality in that L2.
  int bid = blockIdx.x;
  int xcd = bid & 7, idx = bid >> 3;
  int bswz = (xcd < 4 ? xcd * 1563 : 6252 + (xcd - 4) * 1562) + idx;

  const int wid = tid >> 6, lane = tid & 63;
  const int lrow = lane & 15, lk = lane >> 4;
  const int rg = bswz * 64 + wid * 16;     // this wave's base row (sorted edges)

  const int snode = src_s[rg + lrow];
  const int dnode = dst_s[rg + lrow];
  const int eid   = eid_s[rg + lrow];

  // A-fragments straight from global. Per row this is the same 128B random
  // read the staged version issued -- minus the LDS round-trip and barriers.
  short8 af[5];
  af[0] = *(const short8*)(xb + (size_t)snode * 64 + lk * 8);
  af[1] = *(const short8*)(xb + (size_t)snode * 64 + 32 + lk * 8);
  af[2] = *(const short8*)(xb + (size_t)dnode * 64 + lk * 8);
  af[3] = *(const short8*)(xb + (size_t)dnode * 64 + 32 + lk * 8);
  {
    float4 f0 = *(const float4*)(ea + (size_t)eid * 32 + lk * 8);
    float4 f1 = *(const float4*)(ea + (size_t)eid * 32 + lk * 8 + 4);
    u32x4 p;
    asm("v_cvt_pk_bf16_f32 %0, %1, %2" : "=v"(p.x) : "v"(f0.x), "v"(f0.y));
    asm("v_cvt_pk_bf16_f32 %0, %1, %2" : "=v"(p.y) : "v"(f0.z), "v"(f0.w));
    asm("v_cvt_pk_bf16_f32 %0, %1, %2" : "=v"(p.z) : "v"(f1.x), "v"(f1.y));
    asm("v_cvt_pk_bf16_f32 %0, %1, %2" : "=v"(p.w) : "v"(f1.z), "v"(f1.w));
    af[4] = *(short8*)&p;
  }

  // GEMM1: (16x160) @ (160x128) per wave
  f32x4 acc[8] = {};
  #pragma unroll
  for (int c = 0; c < 5; ++c) {
    #pragma unroll
    for (int n = 0; n < 8; ++n) {
      short8 bfr = *(const short8*)(W1p + ((size_t)(c * 128 + n * 16 + lrow) * 4 + lk) * 8);
      acc[n] = __builtin_amdgcn_mfma_f32_16x16x32_bf16(af[c], bfr, acc[n], 0, 0, 0);
    }
  }

  // bias + LayerNorm + SiLU -> wave-private Hs strip
  uint16_t* myH = &Hs[wid * 16 * PH];
  #pragma unroll
  for (int reg = 0; reg < 4; ++reg) {
    float v[8];
    float s = 0.f, ss = 0.f;
    #pragma unroll
    for (int n = 0; n < 8; ++n) {
      v[n] = acc[n][reg] + bf2f(sb1h[n * 16 + lrow]);
      s += v[n]; ss += v[n] * v[n];
    }
    #pragma unroll
    for (int m = 1; m <= 8; m <<= 1) {
      s += __shfl_xor(s, m);
      ss += __shfl_xor(ss, m);
    }
    float mu = s * (1.f / 128.f);
    float rstd = rsqrtf(ss * (1.f / 128.f) - mu * mu + LN_EPS);
    uint16_t* hrow = myH + (lk * 4 + reg) * PH;
    #pragma unroll
    for (int n = 0; n < 8; ++n) {
      int col = n * 16 + lrow;
      float h = (v[n] - mu) * rstd * bf2f(sgh[col]) + bf2f(sbeh[col]);
      h = h / (1.f + __expf(-h));
      hrow[col] = f2bf(h);
    }
  }

  // GEMM2: (16x128) @ (128x128); in-wave LDS write->read ordering via lgkmcnt.
  f32x4 acc2[8] = {};
  const uint16_t* Hbase = myH + lrow * PH + lk * 8;
  #pragma unroll
  for (int c = 0; c < 4; ++c) {
    short8 a = *(const short8*)(Hbase + c * 32);
    #pragma unroll
    for (int n = 0; n < 8; ++n) {
      short8 bfr = *(const short8*)(W2p + ((size_t)(c * 128 + n * 16 + lrow) * 4 + lk) * 8);
      acc2[n] = __builtin_amdgcn_mfma_f32_16x16x32_bf16(a, bfr, acc2[n], 0, 0, 0);
    }
  }

  // In-register f32 segmented reduction over this wave's 16 sorted rows.
  // Run boundaries are wave-uniform (ballot); per-run column sums via
  // predicated adds over acc2 + xor-reduce over the 4 lk groups.
  {
    int dprev = __shfl(dnode, lane - 1);
    bool bnd = (lrow == 0) || (dnode != dprev);
    unsigned long long mask = __ballot(bnd) & 0xFFFFull;
    float b2a = bf2f(sb2h[lk * 32 + lrow]);
    float b2b = bf2f(sb2h[lk * 32 + 16 + lrow]);
    while (mask) {
      int i = (int)__ffsll((long long)mask) - 1;
      unsigned long long rest = mask & (mask - 1);
      int j = rest ? (int)__ffsll((long long)rest) - 1 : 16;
      mask = rest;
      int drun = __shfl(dnode, i);
      float cnt = (float)(j - i);
      float vout0 = 0.f, vout1 = 0.f;
      #pragma unroll
      for (int n = 0; n < 8; ++n) {
        float s = 0.f;
        #pragma unroll
        for (int reg = 0; reg < 4; ++reg) {
          int row = lk * 4 + reg;
          s += (row >= i && row < j) ? acc2[n][reg] : 0.f;
        }
        s += __shfl_xor(s, 16);
        s += __shfl_xor(s, 32);
        if ((n >> 1) == lk) { if (n & 1) vout1 = s; else vout0 = s; }
      }
      float* aggrow = agg + (size_t)drun * HIDDEN;
      atomicAdd(aggrow + lk * 32 + lrow,      vout0 + cnt * b2a);
      atomicAdd(aggrow + lk * 32 + 16 + lrow, vout1 + cnt * b2b);
    }
  }
}

// ---------------- update kernel (overlaid LDS, R6 version) ----------------

__global__ __launch_bounds__(256) void upd_kernel(
    const float* __restrict__ x, const uint16_t* __restrict__ xb,
    const float* __restrict__ agg,
    const uint16_t* __restrict__ Wu1p, const float* __restrict__ b1,
    const float* __restrict__ g1, const float* __restrict__ be1,
    const uint16_t* __restrict__ Wu2p, const float* __restrict__ b2,
    float* __restrict__ out) {
  __shared__ __align__(16) uint16_t A[64 * PU];
  __shared__ float sb1[128], sg[128], sbe[128], sb2[64];

  const int tid = threadIdx.x;
  const int n0 = blockIdx.x * 64;

  if (tid < 128) { sb1[tid] = b1[tid]; sg[tid] = g1[tid]; }
  else { sbe[tid - 128] = be1[tid - 128]; if (tid < 192) sb2[tid - 128] = b2[tid - 128]; }

  #pragma unroll
  for (int it = 0; it < 2; ++it) {
    int u = tid + it * 256;
    int r = u >> 3, q = u & 7;
    int node = min(n0 + r, N_NODES - 1);
    uint4 vs = *(const uint4*)(xb + (size_t)node * 64 + q * 8);
    *(uint4*)(&A[r * PU + q * 8]) = vs;
  }
  #pragma unroll
  for (int it = 0; it < 8; ++it) {
    int u = tid + it * 256;
    int r = u >> 5, q = u & 31;
    int node = min(n0 + r, N_NODES - 1);
    float4 f = *(const float4*)(agg + (size_t)node * HIDDEN + q * 4);
    ushort4 o;
    o.x = f2bf(f.x); o.y = f2bf(f.y); o.z = f2bf(f.z); o.w = f2bf(f.w);
    *(ushort4*)(&A[r * PU + 64 + q * 4]) = o;
  }
  __syncthreads();

  const int wid = tid >> 6, lane = tid & 63;
  const int lrow = lane & 15, lk = lane >> 4;
  const int r0 = wid * 16;

  // GEMM1: (64x192) @ (192x128)
  f32x4 acc[8] = {};
  const uint16_t* Abase = &A[(r0 + lrow) * PU + lk * 8];
  #pragma unroll
  for (int c = 0; c < 6; ++c) {
    short8 a = *(const short8*)(Abase + c * 32);
    #pragma unroll
    for (int n = 0; n < 8; ++n) {
      short8 b = *(const short8*)(Wu1p + ((size_t)((c * 128) + (n * 16 + lrow)) * 4 + lk) * 8);
      acc[n] = __builtin_amdgcn_mfma_f32_16x16x32_bf16(a, b, acc[n], 0, 0, 0);
    }
  }

  // bias + LN + SiLU -> Hs (strip overlay on A)
  uint16_t* strip = &A[r0 * PU];
  #pragma unroll
  for (int reg = 0; reg < 4; ++reg) {
    float v[8];
    float s = 0.f, ss = 0.f;
    #pragma unroll
    for (int n = 0; n < 8; ++n) {
      v[n] = acc[n][reg] + sb1[n * 16 + lrow];
      s += v[n]; ss += v[n] * v[n];
    }
    #pragma unroll
    for (int m = 1; m <= 8; m <<= 1) {
      s += __shfl_xor(s, m);
      ss += __shfl_xor(ss, m);
    }
    float mu = s * (1.f / 128.f);
    float rstd = rsqrtf(ss * (1.f / 128.f) - mu * mu + LN_EPS);
    uint16_t* hrow = strip + (lk * 4 + reg) * PH;
    #pragma unroll
    for (int n = 0; n < 8; ++n) {
      int col = n * 16 + lrow;
      float h = (v[n] - mu) * rstd * sg[col] + sbe[col];
      h = h / (1.f + __expf(-h));
      hrow[col] = f2bf(h);
    }
  }

  // GEMM2: (64x128) @ (128x64)
  f32x4 acc2[4] = {};
  const uint16_t* Hbase = strip + lrow * PH + lk * 8;
  #pragma unroll
  for (int c = 0; c < 4; ++c) {
    short8 a = *(const short8*)(Hbase + c * 32);
    #pragma unroll
    for (int n = 0; n < 4; ++n) {
      short8 b = *(const short8*)(Wu2p + ((size_t)((c * 64) + (n * 16 + lrow)) * 4 + lk) * 8);
      acc2[n] = __builtin_amdgcn_mfma_f32_16x16x32_bf16(a, b, acc2[n], 0, 0, 0);
    }
  }

  // residual + bias + store f32
  #pragma unroll
  for (int reg = 0; reg < 4; ++reg) {
    int node = n0 + r0 + lk * 4 + reg;
    if (node < N_NODES) {
      #pragma unroll
      for (int n = 0; n < 4; ++n) {
        int col = n * 16 + lrow;
        out[(size_t)node * 64 + col] =
            x[(size_t)node * 64 + col] + acc2[n][reg] + sb2[col];
      }
    }
  }
}

extern "C" void kernel_launch(void* const* d_in, const int* in_sizes, int n_in,
                              void* d_out, int out_size, void* d_ws, size_t ws_size,
                              hipStream_t stream) {
  const float* x   = (const float*)d_in[0];
  const int*   ei  = (const int*)d_in[1];
  const float* ea  = (const float*)d_in[2];
  const float* W1  = (const float*)d_in[3];
  const float* b1  = (const float*)d_in[4];
  const float* g1  = (const float*)d_in[5];
  const float* be1 = (const float*)d_in[6];
  const float* W2  = (const float*)d_in[7];
  const float* b2  = (const float*)d_in[8];
  const float* Wu1 = (const float*)d_in[9];
  const float* bu1 = (const float*)d_in[10];
  const float* gu  = (const float*)d_in[11];
  const float* beu = (const float*)d_in[12];
  const float* Wu2 = (const float*)d_in[13];
  const float* bu2 = (const float*)d_in[14];
  float* out = (float*)d_out;

  char* ws = (char*)d_ws;
  float*    agg    = (float*)ws;                      // 51,200,000
  uint16_t* xb     = (uint16_t*)(ws + 51200000);      // 12,800,000
  uint16_t* W1p    = (uint16_t*)(ws + 64000000);      // 40,960
  uint16_t* W2p    = (uint16_t*)(ws + 64040960);      // 32,768
  uint16_t* Wu1p   = (uint16_t*)(ws + 64073728);      // 49,152
  uint16_t* Wu2p   = (uint16_t*)(ws + 64122880);      // 16,384
  int*      cnt    = (int*)(ws + 64139264);           // 400,000
  int*      offs   = (int*)(ws + 64539264);           // 400,000
  int*      cursor = (int*)(ws + 64939264);           // 400,000
  int*      bsum   = (int*)(ws + 65339264);           // 512
  int*      src_s  = (int*)(ws + 65339776);           // 3,200,000
  int*      dst_s  = (int*)(ws + 68539776);           // 3,200,000
  int*      eid_s  = (int*)(ws + 71739776);           // 3,200,000  (end ~74.9 MB)

  hipMemsetAsync(agg, 0, (size_t)N_NODES * HIDDEN * 4, stream);
  hipMemsetAsync(cnt, 0, (size_t)N_NODES * 4, stream);

  prep_kernel<<<PREP_CVT_BLKS + PREP_HIST_BLKS + 272, 256, 0, stream>>>(
      x, xb, ei, cnt, W1, W1p, W2, W2p, Wu1, Wu1p, Wu2, Wu2p);

  scan_blk<<<NB_SCAN, 256, 0, stream>>>(cnt, offs, bsum);
  scan_top<<<1, 128, 0, stream>>>(bsum);
  scan_add<<<(N_NODES + 255) / 256, 256, 0, stream>>>(offs, bsum, cursor);
  scatter_edges<<<(N_EDGES + 255) / 256, 256, 0, stream>>>(ei, cursor, src_s, dst_s, eid_s);

  msg_kernel<<<MSG_NWG, 256, 0, stream>>>(src_s, dst_s, eid_s, ea, xb,
                                          W1p, b1, g1, be1, W2p, b2, agg);
  upd_kernel<<<(N_NODES + 63) / 64, 256, 0, stream>>>(x, xb, agg, Wu1p, bu1, gu, beu,
                                                      Wu2p, bu2, out);
}